// Round 1
// 1581.813 us; speedup vs baseline: 1.1863x; 1.1863x over previous
//
#include <hip/hip_runtime.h>

#define B_ 16384
#define T_ 60
#define H_ 128
#define LDST 296   // A-tile row stride in u16 (K=288 + 8 pad)

typedef unsigned short u16;
typedef short bf16x8 __attribute__((ext_vector_type(8)));
typedef float f32x4 __attribute__((ext_vector_type(4)));

__device__ __forceinline__ u16 f2bf(float f) {
  union { float f; unsigned int u; } v; v.f = f;
  unsigned int r = v.u + 0x7fffu + ((v.u >> 16) & 1u);
  return (u16)(r >> 16);
}
__device__ __forceinline__ float bf2f(u16 b) {
  union { unsigned int u; float f; } v; v.u = ((unsigned int)b) << 16;
  return v.f;
}
__device__ __forceinline__ float sigm(float x) {
  return __builtin_amdgcn_rcpf(1.f + __expf(-x));
}
__device__ __forceinline__ float tanh_f(float x) {
  return 1.f - 2.f * __builtin_amdgcn_rcpf(1.f + __expf(2.f * x));
}

// ---------------------------------------------------------------------------
// prep: pack weights into MFMA B-fragment order, n = torch gate row (g*128+j).
// wfrag[((c*32+nt)*64+lane)*8+jj] = W[k = c*32+(lane>>4)*8+jj][n = nt*16+(lane&15)]
// Also fold Wout@Wlat -> Wco [4][128], bco[4].  (unchanged from baseline)
// ---------------------------------------------------------------------------
__global__ void prep_kernel(const float* __restrict__ Wih1, const float* __restrict__ Whh1,
                            const float* __restrict__ Wih2, const float* __restrict__ Whh2,
                            const float* __restrict__ Wlat, const float* __restrict__ blat,
                            const float* __restrict__ Wout, const float* __restrict__ bout,
                            u16* __restrict__ wfrag1, u16* __restrict__ wfrag2,
                            float* __restrict__ Wco, float* __restrict__ bco) {
  const int N1 = 9 * 32 * 64;   // 18432 lane-groups of 8
  const int N2 = 8 * 32 * 64;   // 16384
  const int total = N1 + N2 + 512 + 4;
  for (int idx = blockIdx.x * blockDim.x + threadIdx.x; idx < total;
       idx += gridDim.x * blockDim.x) {
    if (idx < N1) {
      int c = idx >> 11;
      int rem = idx & 2047;
      int nt = rem >> 6, lane = rem & 63;
      int n = nt * 16 + (lane & 15);        // torch gate row directly
      int kb = c * 32 + (lane >> 4) * 8;
      u16* dst = wfrag1 + (size_t)idx * 8;
      for (int jj = 0; jj < 8; ++jj) {
        int k = kb + jj;
        float x;
        if (k < 128)      x = Wih1[n * 132 + 4 + k];        // mem features
        else if (k < 256) x = Whh1[n * 128 + (k - 128)];    // h features
        else if (k < 260) x = Wih1[n * 132 + (k - 256)];    // x features
        else              x = 0.f;                          // pad
        dst[jj] = f2bf(x);
      }
    } else if (idx < N1 + N2) {
      int i2 = idx - N1;
      int c = i2 >> 11;
      int rem = i2 & 2047;
      int nt = rem >> 6, lane = rem & 63;
      int n = nt * 16 + (lane & 15);
      int kb = c * 32 + (lane >> 4) * 8;
      u16* dst = wfrag2 + (size_t)i2 * 8;
      for (int jj = 0; jj < 8; ++jj) {
        int k = kb + jj;
        float x = (k < 128) ? Wih2[n * 128 + k] : Whh2[n * 128 + (k - 128)];
        dst[jj] = f2bf(x);
      }
    } else if (idx < N1 + N2 + 512) {
      int i = idx - (N1 + N2);
      int y = i >> 7, k = i & 127;
      float acc = 0.f;
      for (int j = 0; j < 128; ++j) acc = fmaf(Wout[y * 128 + j], Wlat[j * 128 + k], acc);
      Wco[i] = acc;
    } else {
      int y = idx - (N1 + N2 + 512);
      float acc = bout[y];
      for (int j = 0; j < 128; ++j) acc = fmaf(Wout[y * 128 + j], blat[j], acc);
      bco[y] = acc;
    }
  }
}

// ---------------------------------------------------------------------------
// MFMA core, register-resident weights.
// mfma_x: the k=256..287 chunk (x features + pad) from per-step streamed bx
//         (consumed FIRST so bx registers die before the main block).
// mfma_w: NC chunks from the statically-indexed wreg file (zero VMEM).
// ---------------------------------------------------------------------------
__device__ __forceinline__ void mfma_x(const u16* __restrict__ As, const bf16x8 bx[4],
                                       int lane, f32x4 acc[4][4]) {
  const int lr = lane & 15, lq = lane >> 4;
  const u16* ab = As + lr * LDST + lq * 8;
  bf16x8 af[4];
#pragma unroll
  for (int mt = 0; mt < 4; ++mt)
    af[mt] = *(const bf16x8*)(ab + mt * (16 * LDST) + 256);
#pragma unroll
  for (int g = 0; g < 4; ++g)
#pragma unroll
    for (int mt = 0; mt < 4; ++mt)
      acc[mt][g] = __builtin_amdgcn_mfma_f32_16x16x32_bf16(af[mt], bx[g], acc[mt][g], 0, 0, 0);
}

template <int NC>
__device__ __forceinline__ void mfma_w(const u16* __restrict__ As,
                                       const bf16x8* __restrict__ wreg,
                                       int lane, f32x4 acc[4][4]) {
  const int lr = lane & 15, lq = lane >> 4;
  const u16* ab = As + lr * LDST + lq * 8;
#pragma unroll
  for (int c = 0; c < NC; ++c) {
    bf16x8 af[4];
#pragma unroll
    for (int mt = 0; mt < 4; ++mt)
      af[mt] = *(const bf16x8*)(ab + mt * (16 * LDST) + c * 32);
#pragma unroll
    for (int g = 0; g < 4; ++g)
#pragma unroll
      for (int mt = 0; mt < 4; ++mt)
        acc[mt][g] = __builtin_amdgcn_mfma_f32_16x16x32_bf16(af[mt], wreg[c * 4 + g], acc[mt][g], 0, 0, 0);
  }
}

// load 8 K-chunks x 4 gate-tiles of this wave's B slice into registers (128 VGPR)
__device__ __forceinline__ void load_wreg(const u16* __restrict__ wfrag, int w, int lane,
                                          bf16x8* __restrict__ wreg) {
  const u16* bb = wfrag + (size_t)(w * 512 + lane * 8);
#pragma unroll
  for (int c = 0; c < 8; ++c)
#pragma unroll
    for (int g = 0; g < 4; ++g)
      wreg[c * 4 + g] = *(const bf16x8*)(bb + (size_t)c * 16384 + g * 4096);
}

// cell update fully in-register: acc[mt][gate][reg], gates of a j are in-lane.
__device__ __forceinline__ void cell_update(f32x4 acc[4][4], float4 bz,
                                            float* __restrict__ cr, u16* __restrict__ hb) {
#pragma unroll
  for (int mt = 0; mt < 4; ++mt)
#pragma unroll
    for (int r = 0; r < 4; ++r) {
      int idx = mt * 4 + r;
      float gi = sigm(acc[mt][0][r] + bz.x);
      float gf = sigm(acc[mt][1][r] + bz.y);
      float gg = tanh_f(acc[mt][2][r] + bz.z);
      float go = sigm(acc[mt][3][r] + bz.w);
      float c = gf * cr[idx] + gi * gg;
      cr[idx] = c;
      hb[idx] = f2bf(go * tanh_f(c));
    }
}

// dot of 8 bf16 h values (packed uint4) with 8 fp32 weights
__device__ __forceinline__ float dot8w(uint4 hu, const float* __restrict__ wp, float a) {
  const unsigned* h = (const unsigned*)&hu;
#pragma unroll
  for (int i = 0; i < 4; ++i) {
    union { unsigned u; float f; } hl, hh;
    hl.u = h[i] << 16; hh.u = h[i] & 0xffff0000u;
    a = fmaf(hl.f, wp[2 * i], a);
    a = fmaf(hh.f, wp[2 * i + 1], a);
  }
  return a;
}

// ---------------------------------------------------------------------------
// Persistent kernel: 256 blocks x 512 threads. Block owns 64 batch rows for
// all 120 steps. h in LDS A-tile, c in registers, weights in registers.
// ---------------------------------------------------------------------------
__global__ __launch_bounds__(512, 2) void rnn_persist(
    const float* __restrict__ inputs_main, const float* __restrict__ inputs_sfc,
    const float* __restrict__ rnn1_mem0, const float* __restrict__ hx2,
    const float* __restrict__ cx2,
    const float* __restrict__ Ws1, const float* __restrict__ bs1,
    const float* __restrict__ Ws2, const float* __restrict__ bs2,
    const float* __restrict__ bih1, const float* __restrict__ bhh1,
    const float* __restrict__ bih2, const float* __restrict__ bhh2,
    const float* __restrict__ Wsfc, const float* __restrict__ bsfc,
    const u16* __restrict__ wfrag1, const u16* __restrict__ wfrag2,
    const float* __restrict__ Wco, const float* __restrict__ bco,
    u16* __restrict__ r1buf, float* __restrict__ out, float* __restrict__ out_sfc) {
  __shared__ __align__(16) u16 As[64 * LDST];   // 37888 B
  __shared__ __align__(16) float WcoS[4 * 132]; // fp32 for epilogue accuracy
  __shared__ __align__(16) float WsfcS[3 * 132];

  const int tid = threadIdx.x;
  const int w = tid >> 6, lane = tid & 63, lr = lane & 15, lq = lane >> 4;
  const int jg = w * 16 + lr;                   // this lane's j (0..127)
  const size_t row0 = (size_t)blockIdx.x * 64;

  // hoisted per-lane constants (bz reused for phase 2 at the transition)
  float4 bz = make_float4(bih1[jg] + bhh1[jg], bih1[128 + jg] + bhh1[128 + jg],
                          bih1[256 + jg] + bhh1[256 + jg], bih1[384 + jg] + bhh1[384 + jg]);
  const float bcoy = bco[tid & 3];

  // Wco/Wsfc -> LDS fp32 (padded stride 132)
  if (tid < 512) WcoS[(tid >> 7) * 132 + (tid & 127)] = Wco[tid];
  if (tid < 384) WsfcS[(tid >> 7) * 132 + (tid & 127)] = Wsfc[tid];

  // zero k256..287 region once (x overwrites 256..259; pad stays 0)
#pragma unroll
  for (int kk = 0; kk < 4; ++kk) {
    int f = tid + kk * 512;
    As[(f >> 5) * LDST + 256 + (f & 31)] = 0;
  }

  // register-resident weight file: phase-1 chunks c=0..7 (k=0..255).
  // Chunk c=8 (x+pad) is streamed per step from a perma-hot 32 KB L2 region.
  bf16x8 wreg[32];
  load_wreg(wfrag1, w, lane, wreg);
  const u16* bxp = wfrag1 + (size_t)(w * 512 + lane * 8) + (size_t)8 * 16384;

  float cr[16];
  u16 hb[16];
  // init h1 = tanh(sfc@Ws1^T+bs1) -> LDS h-region, c1 = tanh(sfc@Ws2^T+bs2) -> regs
  {
    float w1a = Ws1[jg * 3], w1b = Ws1[jg * 3 + 1], w1c = Ws1[jg * 3 + 2], b1 = bs1[jg];
    float w2a = Ws2[jg * 3], w2b = Ws2[jg * 3 + 1], w2c = Ws2[jg * 3 + 2], b2 = bs2[jg];
#pragma unroll
    for (int mt = 0; mt < 4; ++mt)
#pragma unroll
      for (int r = 0; r < 4; ++r) {
        int rl = mt * 16 + lq * 4 + r;
        const float* sp = inputs_sfc + (row0 + rl) * 3;
        float s0 = sp[0], s1 = sp[1], s2 = sp[2];
        float h0 = tanh_f(fmaf(s2, w1c, fmaf(s1, w1b, fmaf(s0, w1a, b1))));
        cr[mt * 4 + r] = tanh_f(fmaf(s2, w2c, fmaf(s1, w2b, fmaf(s0, w2a, b2))));
        As[rl * LDST + 128 + jg] = f2bf(h0);
      }
  }
  // stage mem_0 (k0..127) and x_0 (k256..259)
#pragma unroll
  for (int kk = 0; kk < 4; ++kk) {
    int f = tid + kk * 512, row = f >> 5, i = f & 31;
    float4 v = *(const float4*)(rnn1_mem0 + (row0 + row) * (T_ * H_) + i * 4);
    *(ushort4*)&As[row * LDST + i * 4] =
        make_ushort4(f2bf(v.x), f2bf(v.y), f2bf(v.z), f2bf(v.w));
  }
  if (tid < 64) {
    float4 v = *(const float4*)(inputs_main + ((row0 + tid) * T_ + 59) * 4);
    *(ushort4*)&As[tid * LDST + 256] = make_ushort4(f2bf(v.x), f2bf(v.y), f2bf(v.z), f2bf(v.w));
  }
  __syncthreads();

  // ================= LSTM1: s = 0..59 =================
#pragma unroll 1
  for (int s = 0; s < T_; ++s) {
    // coalesced r1 store of slab s-1 (h(s-1) sits in As h-region right now).
    // Slab 59 is never read back from r1buf (phase 2 gets it via the
    // transition copy), so it is never stored.
    if (s > 0) {
#pragma unroll
      for (int kk = 0; kk < 2; ++kk) {
        int f = tid + kk * 512;
        uint4 hv = *(const uint4*)&As[(f >> 4) * LDST + 128 + (f & 15) * 8];
        *(uint4*)(r1buf + ((size_t)(s - 1) * B_ + row0 + (f >> 4)) * H_ + (f & 15) * 8) = hv;
      }
    }
    // stream the tiny x-chunk weights (32 KB shared by all blocks -> L2 hot)
    bf16x8 bx[4];
#pragma unroll
    for (int g = 0; g < 4; ++g) bx[g] = *(const bf16x8*)(bxp + g * 4096);

    f32x4 acc[4][4];
#pragma unroll
    for (int mt = 0; mt < 4; ++mt)
#pragma unroll
      for (int g = 0; g < 4; ++g) acc[mt][g] = (f32x4){0.f, 0.f, 0.f, 0.f};
    mfma_x(As, bx, lane, acc);          // c=8 first: bx dies before main block
    mfma_w<8>(As, wreg, lane, acc);     // c=0..7 pure LDS+MFMA, zero VMEM

    // next-slab prefetch issued here; latency hides under cell_update+barrier
    const int sn = (s < 59) ? s + 1 : 59;
    float4 mv[4];
#pragma unroll
    for (int kk = 0; kk < 4; ++kk) {
      int f = tid + kk * 512;
      mv[kk] = *(const float4*)(rnn1_mem0 + (row0 + (f >> 5)) * (T_ * H_) + sn * 128 + (f & 31) * 4);
    }
    float4 xv = make_float4(0, 0, 0, 0);
    if (tid < 64) xv = *(const float4*)(inputs_main + ((row0 + tid) * T_ + (59 - sn)) * 4);

    cell_update(acc, bz, cr, hb);
    __syncthreads();
    // write new h + next mem/x into A-tile
#pragma unroll
    for (int mt = 0; mt < 4; ++mt)
#pragma unroll
      for (int r = 0; r < 4; ++r)
        As[(mt * 16 + lq * 4 + r) * LDST + 128 + jg] = hb[mt * 4 + r];
#pragma unroll
    for (int kk = 0; kk < 4; ++kk) {
      int f = tid + kk * 512, row = f >> 5, i = f & 31;
      *(ushort4*)&As[row * LDST + i * 4] =
          make_ushort4(f2bf(mv[kk].x), f2bf(mv[kk].y), f2bf(mv[kk].z), f2bf(mv[kk].w));
    }
    if (tid < 64)
      *(ushort4*)&As[tid * LDST + 256] = make_ushort4(f2bf(xv.x), f2bf(xv.y), f2bf(xv.z), f2bf(xv.w));
    __syncthreads();
  }

  // ============ transition: r1[t=0] = h-region -> k0; init h2/c2 ============
  {
    // FULL-WIDTH copy: 2 x uint4 per thread = 64 rows x 128 u16
    uint4 cv[2];
#pragma unroll
    for (int kk = 0; kk < 2; ++kk) {
      int f = tid + kk * 512;
      cv[kk] = *(const uint4*)&As[(f >> 4) * LDST + 128 + (f & 15) * 8];
    }
    // swap in phase-2 constants/weights (no LDS dependence)
    bz = make_float4(bih2[jg] + bhh2[jg], bih2[128 + jg] + bhh2[128 + jg],
                     bih2[256 + jg] + bhh2[256 + jg], bih2[384 + jg] + bhh2[384 + jg]);
    load_wreg(wfrag2, w, lane, wreg);
    __syncthreads();
#pragma unroll
    for (int kk = 0; kk < 2; ++kk) {
      int f = tid + kk * 512;
      *(uint4*)&As[(f >> 4) * LDST + (f & 15) * 8] = cv[kk];
    }
#pragma unroll
    for (int mt = 0; mt < 4; ++mt)
#pragma unroll
      for (int r = 0; r < 4; ++r) {
        int rl = mt * 16 + lq * 4 + r;
        size_t gi = (row0 + rl) * H_ + jg;
        cr[mt * 4 + r] = cx2[gi];
        As[rl * LDST + 128 + jg] = f2bf(hx2[gi]);
      }
    __syncthreads();
  }

  // ================= LSTM2: t = 0..59 (input slab = 59-t) =================
#pragma unroll 1
  for (int t = 0; t < T_; ++t) {
    const int slabn = (t < 59) ? (58 - t) : 0;
    uint4 rv[2];
#pragma unroll
    for (int kk = 0; kk < 2; ++kk) {
      int f = tid + kk * 512;
      rv[kk] = *(const uint4*)(r1buf + ((size_t)slabn * B_ + row0 + (f >> 4)) * H_ + (f & 15) * 8);
    }
    f32x4 acc[4][4];
#pragma unroll
    for (int mt = 0; mt < 4; ++mt)
#pragma unroll
      for (int g = 0; g < 4; ++g) acc[mt][g] = (f32x4){0.f, 0.f, 0.f, 0.f};
    mfma_w<8>(As, wreg, lane, acc);     // K=256, all weights register-resident
    cell_update(acc, bz, cr, hb);
    __syncthreads();
#pragma unroll
    for (int mt = 0; mt < 4; ++mt)
#pragma unroll
      for (int r = 0; r < 4; ++r)
        As[(mt * 16 + lq * 4 + r) * LDST + 128 + jg] = hb[mt * 4 + r];
#pragma unroll
    for (int kk = 0; kk < 2; ++kk) {
      int f = tid + kk * 512;
      *(uint4*)&As[(f >> 4) * LDST + (f & 15) * 8] = rv[kk];
    }
    __syncthreads();
    // fused out = h2 @ Wco^T + bco  (quarter of threads reduce from LDS h)
    if (tid < 256) {
      int row = tid >> 2, y = tid & 3;
      float a = bcoy;
      const u16* hrow = As + row * LDST + 128;
      const float* wrow = WcoS + y * 132;
#pragma unroll
      for (int sg = 0; sg < 16; ++sg)
        a = dot8w(*(const uint4*)(hrow + sg * 8), wrow + sg * 8, a);
      out[((row0 + row) * T_ + t) * 4 + y] = a;
    }
    if (t == 59 && tid >= 256) {
      int q = tid - 256;
      int row = q >> 2, y = q & 3;
      if (y < 3) {
        float a = bsfc[y];
        const u16* hrow = As + row * LDST + 128;
        const float* wrow = WsfcS + y * 132;
#pragma unroll
        for (int sg = 0; sg < 16; ++sg)
          a = dot8w(*(const uint4*)(hrow + sg * 8), wrow + sg * 8, a);
        out_sfc[(row0 + row) * 3 + y] = a;
      }
    }
  }
}

// ---------------------------------------------------------------------------
extern "C" void kernel_launch(void* const* d_in, const int* in_sizes, int n_in,
                              void* d_out, int out_size, void* d_ws, size_t ws_size,
                              hipStream_t stream) {
  (void)in_sizes; (void)n_in; (void)out_size;
  const float* inputs_main = (const float*)d_in[0];
  const float* inputs_sfc  = (const float*)d_in[1];
  const float* rnn1_mem0   = (const float*)d_in[2];
  const float* hx2         = (const float*)d_in[3];
  const float* cx2         = (const float*)d_in[4];
  const float* Ws1  = (const float*)d_in[5];
  const float* bs1  = (const float*)d_in[6];
  const float* Ws2  = (const float*)d_in[7];
  const float* bs2  = (const float*)d_in[8];
  const float* Wih1 = (const float*)d_in[9];
  const float* Whh1 = (const float*)d_in[10];
  const float* bih1 = (const float*)d_in[11];
  const float* bhh1 = (const float*)d_in[12];
  const float* Wih2 = (const float*)d_in[13];
  const float* Whh2 = (const float*)d_in[14];
  const float* bih2 = (const float*)d_in[15];
  const float* bhh2 = (const float*)d_in[16];
  const float* Wlat = (const float*)d_in[17];
  const float* blat = (const float*)d_in[18];
  const float* Wout = (const float*)d_in[19];
  const float* bout = (const float*)d_in[20];
  const float* Wsfc = (const float*)d_in[21];
  const float* bsfc = (const float*)d_in[22];

  float* out = (float*)d_out;                        // [B,60,4]
  float* out_sfc = out + (size_t)B_ * T_ * 4;        // [B,3]

  char* p = (char*)d_ws;
  u16* wfrag1 = (u16*)p; p += 294912;                // 9*32*64*8 bf16
  u16* wfrag2 = (u16*)p; p += 262144;                // 8*32*64*8 bf16
  float* Wco  = (float*)p; p += 2048;
  float* bco  = (float*)p; p += 64;
  u16* r1buf  = (u16*)p; p += (size_t)T_ * B_ * H_ * 2;
  if ((size_t)(p - (char*)d_ws) > ws_size) return;

  prep_kernel<<<139, 256, 0, stream>>>(Wih1, Whh1, Wih2, Whh2, Wlat, blat, Wout, bout,
                                       wfrag1, wfrag2, Wco, bco);
  rnn_persist<<<256, 512, 0, stream>>>(inputs_main, inputs_sfc, rnn1_mem0, hx2, cx2,
                                       Ws1, bs1, Ws2, bs2,
                                       bih1, bhh1, bih2, bhh2, Wsfc, bsfc,
                                       wfrag1, wfrag2, Wco, bco,
                                       r1buf, out, out_sfc);
}